// Round 14
// baseline (11435.914 us; speedup 1.0000x reference)
//
#include <hip/hip_runtime.h>

typedef _Float16 half_t;
typedef _Float16 f16x8 __attribute__((ext_vector_type(8)));
typedef _Float16 f16x4 __attribute__((ext_vector_type(4)));
typedef float f32x4 __attribute__((ext_vector_type(4)));
typedef unsigned int uint2v __attribute__((ext_vector_type(2)));

#define T_LEN 512
#define BATCH 128
#define INDIM 800
#define HID   400
#define NG    3200   // 2 dirs * 4H
#define KP    416    // recurrent K padded to 13*32
#define BPD   50     // scan blocks per direction
#define UPB   8      // units per scan block (32 gate rows)
#define GEMM_BLKS (512 * 25)

// coherent-at-LLC access (bypass L1+L2) -----------------------------------
__device__ __forceinline__ f32x4 ld_coh_128(const void* p) {
    f32x4 r;
    asm volatile("global_load_dwordx4 %0, %1, off sc0 sc1" : "=v"(r) : "v"(p) : "memory");
    return r;
}
__device__ __forceinline__ void st_coh_64(void* p, uint2v v) {
    asm volatile("global_store_dwordx2 %0, %1, off sc0 sc1" :: "v"(p), "v"(v) : "memory");
}
__device__ __forceinline__ void st_coh_32(void* p, int v) {
    asm volatile("global_store_dword %0, %1, off sc0 sc1" :: "v"(p), "v"(v) : "memory");
}
__device__ __forceinline__ int ld_coh_32(const void* p) {
    int v;
    asm volatile("global_load_dword %0, %1, off sc0 sc1\ns_waitcnt vmcnt(0)"
                 : "=v"(v) : "v"(p) : "memory");
    return v;
}

// ---------------- cast fp32 -> fp16 ----------------
__global__ void cast_f32_f16(const float* __restrict__ src, half_t* __restrict__ dst, size_t n) {
    size_t i = (size_t)blockIdx.x * blockDim.x + threadIdx.x;
    size_t stride = (size_t)gridDim.x * blockDim.x;
    for (; i < n; i += stride) dst[i] = (half_t)src[i];
}

// ---------------- standalone input GEMM (layer 0 only) ----------------
// A[M=T*B, 800] @ W[3200, 800]^T, output TRANSPOSED per t-tile:
// gates_T[((t*3200)+n)*128 + b]   (fp16, fp32 accum)
__global__ __launch_bounds__(256)
void gemm_f16(const half_t* __restrict__ A, const half_t* __restrict__ Bw,
              half_t* __restrict__ C) {
    __shared__ half_t As[128 * 32];
    __shared__ half_t Bs[128 * 32];
    const int tid  = threadIdx.x;
    const int m0   = blockIdx.x * 128;
    const int n0   = blockIdx.y * 128;
    const int w    = tid >> 6;
    const int lane = tid & 63;
    const int wm   = (w & 1) * 64;
    const int wn   = (w >> 1) * 64;
    const int lr   = lane & 15;
    const int kb   = (lane >> 4) * 8;

    f32x4 acc[4][4] = {};

    for (int k0 = 0; k0 < INDIM; k0 += 32) {
        __syncthreads();
        #pragma unroll
        for (int it = 0; it < 2; ++it) {
            int c   = tid + it * 256;
            int row = c >> 2;
            int kp  = (c & 3) * 8;
            *(f16x8*)(As + row * 32 + kp) = *(const f16x8*)(A  + (size_t)(m0 + row) * INDIM + k0 + kp);
            *(f16x8*)(Bs + row * 32 + kp) = *(const f16x8*)(Bw + (size_t)(n0 + row) * INDIM + k0 + kp);
        }
        __syncthreads();
        f16x8 a[4], b[4];
        #pragma unroll
        for (int i = 0; i < 4; ++i) a[i] = *(const f16x8*)(As + (wm + i * 16 + lr) * 32 + kb);
        #pragma unroll
        for (int j = 0; j < 4; ++j) b[j] = *(const f16x8*)(Bs + (wn + j * 16 + lr) * 32 + kb);
        #pragma unroll
        for (int i = 0; i < 4; ++i)
            #pragma unroll
            for (int j = 0; j < 4; ++j)
                acc[i][j] = __builtin_amdgcn_mfma_f32_16x16x32_f16(b[j], a[i], acc[i][j], 0, 0, 0);
    }

    const int t  = blockIdx.x;
    const int lq = lane >> 4;
    #pragma unroll
    for (int i = 0; i < 4; ++i)
        #pragma unroll
        for (int j = 0; j < 4; ++j)
            #pragma unroll
            for (int r = 0; r < 4; ++r) {
                int n  = n0 + wn + j * 16 + lq * 4 + r;
                int bb = wm + i * 16 + lr;
                C[((size_t)t * NG + n) * BATCH + bb] = (half_t)acc[i][j][r];
            }
}

// ---------------- merged: scan(layer l) + GEMM(layer l+1) ----------------
// blocks [0,100): R4 scan verbatim (+ coherent x stores, + final flag 514).
// blocks [100, 100+12800): GEMM tiles, middle-out t order, poll flags until
// x rows for time t are LLC-visible, then standard tile GEMM into gates.
// Big LDS pad => 1 block/CU: GEMM blocks never share a CU with scan blocks.
__global__ __launch_bounds__(256)
void scan_gemm(const float* __restrict__ Whh_all, const float* __restrict__ bih,
               const float* __restrict__ bhh, half_t* __restrict__ gates,
               const int* __restrict__ bs, half_t* __restrict__ h_pub,
               int* __restrict__ flags,
               half_t* __restrict__ out16, float* __restrict__ out32, int layer,
               const half_t* __restrict__ gA, const half_t* __restrict__ gW) {
    __shared__ half_t Wsh[32][424];
    __shared__ half_t As[128 * 32];
    __shared__ half_t Bs[128 * 32];
    __shared__ char   lds_pad[94208];
    if (layer == -777) lds_pad[threadIdx.x] = 1;   // keep allocation (never true)

    const int tid = threadIdx.x;

    if (blockIdx.x < 2 * BPD) {
        // ================= SCAN branch (R4 verbatim + 2 edits) =================
        const int d   = blockIdx.x / BPD;
        const int blk = blockIdx.x % BPD;
        const int u0  = blk * UPB;
        const float* Wbase = Whh_all + (size_t)(layer * 2 + d) * 1600 * HID;

        for (int idx = tid; idx < 32 * KP; idx += 256) {
            int g = idx / KP, k = idx - g * KP;
            int type = g >> 3, usub = g & 7;
            float v = (k < HID) ? Wbase[(size_t)(type * HID + u0 + usub) * HID + k] : 0.f;
            Wsh[g][k] = (half_t)v;
        }

        const int lane = tid & 63, w = tid >> 6;
        const int lr = lane & 15, kq = (lane >> 4) * 8;
        const int b = tid & 127, s = tid >> 7;

        float bias[4][4];
        float c_reg[4] = {0.f, 0.f, 0.f, 0.f}, h_reg[4] = {0.f, 0.f, 0.f, 0.f};
        #pragma unroll
        for (int q = 0; q < 4; ++q) {
            int usub = 4 * s + q;
            #pragma unroll
            for (int ty = 0; ty < 4; ++ty) {
                size_t bi = (size_t)(layer * 2 + d) * 1600 + ty * HID + u0 + usub;
                bias[q][ty] = bih[bi] + bhh[bi];
            }
        }

        const long gstep = (long)(d ? -1 : 1) * (long)NG * BATCH;
        const long ostep = (long)(d ? -1 : 1) * (long)BATCH * 800;
        const int  t0p   = d ? (T_LEN - 1) : 0;
        const half_t* gptr = gates + (size_t)t0p * NG * BATCH + (size_t)d * 1600 * BATCH
                           + (size_t)(u0 + 4 * s) * BATCH + b;
        float*  op32 = out32 ? out32 + (size_t)t0p * BATCH * 800 + (size_t)b * 800 + d * HID + u0 + 4 * s
                             : (float*)nullptr;
        half_t* op16 = out16 ? out16 + (size_t)t0p * BATCH * 800 + (size_t)b * 800 + d * HID + u0 + 4 * s
                             : (half_t*)nullptr;

#define GPRE_LOAD() do {                                                    \
            _Pragma("unroll") for (int q = 0; q < 4; ++q)                   \
                _Pragma("unroll") for (int ty = 0; ty < 4; ++ty)            \
                    gpre[q][ty] = (float)gptr[q * BATCH + ty * HID * BATCH];\
        } while (0)

        float gpre[4][4];
        int bst = bs[t0p];
        bool bact = b < bst;
        if (bact) GPRE_LOAD();

        int* const myflag = flags + d * 64 + blk;
        int cur = 0;
        __syncthreads();

        for (int t = 0; t < T_LEN; ++t) {
            const bool last = (t == T_LEN - 1);
            const half_t* hcur = h_pub + (size_t)(cur * 2 + d) * BATCH * KP;

            const bool act0 = (w * 32) < bst;
            const bool act1 = (w * 32 + 16) < bst;
            f32x4 hb0[13], hb1[13];
            const half_t* p0 = hcur + (size_t)(w * 32 + lr) * KP + kq;
            const half_t* p1 = p0 + 16 * KP;
            if (act0) {
                #pragma unroll
                for (int ks = 0; ks < 13; ++ks) hb0[ks] = ld_coh_128(p0 + ks * 32);
            }
            if (act1) {
                #pragma unroll
                for (int ks = 0; ks < 13; ++ks) hb1[ks] = ld_coh_128(p1 + ks * 32);
            }
            asm volatile("s_waitcnt vmcnt(0)" ::: "memory");
            __builtin_amdgcn_sched_barrier(0);

            f32x4 acc[2][2] = {};
            if (act0) {
                #pragma unroll
                for (int ks = 0; ks < 13; ++ks) {
                    f16x8 a0 = *(const f16x8*)(&Wsh[lr][kq + ks * 32]);
                    f16x8 a1 = *(const f16x8*)(&Wsh[16 + lr][kq + ks * 32]);
                    f16x8 b0 = __builtin_bit_cast(f16x8, hb0[ks]);
                    acc[0][0] = __builtin_amdgcn_mfma_f32_16x16x32_f16(a0, b0, acc[0][0], 0, 0, 0);
                    acc[1][0] = __builtin_amdgcn_mfma_f32_16x16x32_f16(a1, b0, acc[1][0], 0, 0, 0);
                    if (act1) {
                        f16x8 b1 = __builtin_bit_cast(f16x8, hb1[ks]);
                        acc[0][1] = __builtin_amdgcn_mfma_f32_16x16x32_f16(a0, b1, acc[0][1], 0, 0, 0);
                        acc[1][1] = __builtin_amdgcn_mfma_f32_16x16x32_f16(a1, b1, acc[1][1], 0, 0, 0);
                    }
                }
            }
            const int crow = (lane >> 4) * 4;
            __shared__ float Gsh[32][132];
            #pragma unroll
            for (int i = 0; i < 2; ++i) {
                if (act0) {
                    #pragma unroll
                    for (int r = 0; r < 4; ++r)
                        Gsh[i * 16 + crow + r][w * 32 + lr] = acc[i][0][r];
                }
                if (act1) {
                    #pragma unroll
                    for (int r = 0; r < 4; ++r)
                        Gsh[i * 16 + crow + r][w * 32 + 16 + lr] = acc[i][1][r];
                }
            }
            __syncthreads();

            if (bact) {
                #pragma unroll
                for (int q = 0; q < 4; ++q) {
                    int usub = 4 * s + q;
                    float gI = Gsh[usub][b]      + gpre[q][0] + bias[q][0];
                    float gF = Gsh[8 + usub][b]  + gpre[q][1] + bias[q][1];
                    float gG = Gsh[16 + usub][b] + gpre[q][2] + bias[q][2];
                    float gO = Gsh[24 + usub][b] + gpre[q][3] + bias[q][3];
                    float iv = 1.f / (1.f + __expf(-gI));
                    float fv = 1.f / (1.f + __expf(-gF));
                    float gv = 1.f - 2.f / (1.f + __expf(2.f * gG));
                    float ov = 1.f / (1.f + __expf(-gO));
                    float cn = fv * c_reg[q] + iv * gv;
                    float hnew = ov * (1.f - 2.f / (1.f + __expf(2.f * cn)));
                    c_reg[q] = cn; h_reg[q] = hnew;
                }
            }

            if (!last) {
                if (bact) {
                    half_t* hn = h_pub + (size_t)((cur ^ 1) * 2 + d) * BATCH * KP;
                    f16x4 hv4;
                    hv4[0] = (half_t)h_reg[0]; hv4[1] = (half_t)h_reg[1];
                    hv4[2] = (half_t)h_reg[2]; hv4[3] = (half_t)h_reg[3];
                    st_coh_64(hn + (size_t)b * KP + u0 + 4 * s, __builtin_bit_cast(uint2v, hv4));
                }
                asm volatile("s_waitcnt vmcnt(0)" ::: "memory");
                __syncthreads();
                if (tid == 0) st_coh_32(myflag, t + 1);
            }

            // outputs: x (fp16) goes LLC-coherent so merged GEMM can consume it
            if (bact) {
                if (op32) { f32x4 o4 = {h_reg[0], h_reg[1], h_reg[2], h_reg[3]}; *(f32x4*)op32 = o4; }
                else {
                    f16x4 o4;
                    o4[0] = (half_t)h_reg[0]; o4[1] = (half_t)h_reg[1];
                    o4[2] = (half_t)h_reg[2]; o4[3] = (half_t)h_reg[3];
                    st_coh_64(op16, __builtin_bit_cast(uint2v, o4));
                }
            } else {
                if (op32) { f32x4 z = {0.f, 0.f, 0.f, 0.f}; *(f32x4*)op32 = z; }
                else {
                    f16x4 z; z[0] = z[1] = z[2] = z[3] = (half_t)0.f;
                    st_coh_64(op16, __builtin_bit_cast(uint2v, z));
                }
            }
            if (op32) op32 += ostep; else op16 += ostep;

            if (!last) {
                gptr += gstep;
                const int bst_next = bs[d ? (T_LEN - 2 - t) : (t + 1)];
                const bool bact_next = b < bst_next;
                if (bact_next) GPRE_LOAD();
                bst = bst_next; bact = bact_next;

                if (tid < 64) {
                    const int* fp = flags + d * 64 + tid;
                    int pred;
                    do {
                        int v = (tid < BPD) ? ld_coh_32(fp) : 0x7fffffff;
                        pred = (v >= t + 1);
                    } while (!__all(pred));
                }
                __syncthreads();
            }
            cur ^= 1;
        }
#undef GPRE_LOAD
        // final flag: everything (incl. last outputs) drained -> 514
        asm volatile("s_waitcnt vmcnt(0)" ::: "memory");
        __syncthreads();
        if (tid == 0) st_coh_32(myflag, T_LEN + 2);

    } else if (gA) {
        // ================= GEMM branch (layer l+1), middle-out t =================
        const int bid2 = blockIdx.x - 2 * BPD;
        const int o    = bid2 / 25;
        const int nblk = bid2 % 25;
        const int u    = o >> 1;
        const int t    = (o & 1) ? (256 + u) : (255 - u);
        const int m0   = t * 128;
        const int n0   = nblk * 128;

        // readiness: fwd outputs(t) drained when all fwd flags >= t+2;
        // bwd outputs(t) drained when all bwd flags >= 513-t. Final flag = 514.
        if (tid < 64) {
            const int need_f = t + 2;
            const int need_b = T_LEN + 1 - t;
            int pred;
            do {
                int vf = (tid < BPD) ? ld_coh_32(flags + tid) : 0x7fffffff;
                int vb = (tid < BPD) ? ld_coh_32(flags + 64 + tid) : 0x7fffffff;
                pred = (vf >= need_f) & (vb >= need_b);
                if (!__all(pred)) __builtin_amdgcn_s_sleep(10);
                else break;
            } while (1);
        }
        __syncthreads();

        const int w    = tid >> 6;
        const int lane = tid & 63;
        const int wm   = (w & 1) * 64;
        const int wn   = (w >> 1) * 64;
        const int lr   = lane & 15;
        const int kb   = (lane >> 4) * 8;

        f32x4 acc[4][4] = {};

        for (int k0 = 0; k0 < INDIM; k0 += 32) {
            __syncthreads();
            #pragma unroll
            for (int it = 0; it < 2; ++it) {
                int c   = tid + it * 256;
                int row = c >> 2;
                int kp  = (c & 3) * 8;
                *(f16x8*)(As + row * 32 + kp) = *(const f16x8*)(gA + (size_t)(m0 + row) * INDIM + k0 + kp);
                *(f16x8*)(Bs + row * 32 + kp) = *(const f16x8*)(gW + (size_t)(n0 + row) * INDIM + k0 + kp);
            }
            __syncthreads();
            f16x8 a[4], b[4];
            #pragma unroll
            for (int i = 0; i < 4; ++i) a[i] = *(const f16x8*)(As + (wm + i * 16 + lr) * 32 + kb);
            #pragma unroll
            for (int j = 0; j < 4; ++j) b[j] = *(const f16x8*)(Bs + (wn + j * 16 + lr) * 32 + kb);
            #pragma unroll
            for (int i = 0; i < 4; ++i)
                #pragma unroll
                for (int j = 0; j < 4; ++j)
                    acc[i][j] = __builtin_amdgcn_mfma_f32_16x16x32_f16(b[j], a[i], acc[i][j], 0, 0, 0);
        }

        const int lq = lane >> 4;
        #pragma unroll
        for (int i = 0; i < 4; ++i)
            #pragma unroll
            for (int j = 0; j < 4; ++j)
                #pragma unroll
                for (int r = 0; r < 4; ++r) {
                    int n  = n0 + wn + j * 16 + lq * 4 + r;
                    int bb = wm + i * 16 + lr;
                    gates[((size_t)t * NG + n) * BATCH + bb] = (half_t)acc[i][j][r];
                }
    }
}

// ---------------- host ----------------
extern "C" void kernel_launch(void* const* d_in, const int* in_sizes, int n_in,
                              void* d_out, int out_size, void* d_ws, size_t ws_size,
                              hipStream_t stream) {
    const float* x    = (const float*)d_in[0];
    const float* Wih  = (const float*)d_in[1];
    const float* Whh  = (const float*)d_in[2];
    const float* bih  = (const float*)d_in[3];
    const float* bhh  = (const float*)d_in[4];
    const int*   bs   = (const int*)d_in[5];
    float*       out  = (float*)d_out;

    char* ws = (char*)d_ws;
    const size_t XBUF_B  = (size_t)T_LEN * BATCH * INDIM * 2;      // 104,857,600
    const size_t WIH_B   = (size_t)3 * 2 * 1600 * INDIM * 2;       //  15,360,000
    const size_t GATES_B = (size_t)T_LEN * NG * BATCH * 2;         // 419,430,400
    const size_t HPUB_B  = (size_t)2 * 2 * BATCH * KP * 2;         //     425,984

    half_t* xbuf0 = (half_t*)(ws);
    half_t* xbuf1 = (half_t*)(ws + XBUF_B);
    half_t* Wih16 = (half_t*)(ws + 2 * XBUF_B);
    half_t* gates = (half_t*)(ws + 2 * XBUF_B + WIH_B);
    half_t* h_pub = (half_t*)(ws + 2 * XBUF_B + WIH_B + GATES_B);
    int*    flags = (int*)   (ws + 2 * XBUF_B + WIH_B + GATES_B + HPUB_B);
    (void)ws_size; (void)in_sizes; (void)n_in; (void)out_size;

    cast_f32_f16<<<2048, 256, 0, stream>>>(x,   xbuf0, (size_t)T_LEN * BATCH * INDIM);
    cast_f32_f16<<<2048, 256, 0, stream>>>(Wih, Wih16, (size_t)3 * 2 * 1600 * INDIM);

    // layer-0 gates: standalone full-machine GEMM
    gemm_f16<<<dim3(512, 25), 256, 0, stream>>>(xbuf0, Wih16, gates);

    for (int l = 0; l < 3; ++l) {
        half_t*       xout16 = (l == 0) ? xbuf1 : ((l == 1) ? xbuf0 : (half_t*)nullptr);
        float*        out32  = (l == 2) ? out : (float*)nullptr;
        const half_t* gA     = xout16;                              // next GEMM's A = this scan's x-out
        const half_t* gW     = (l < 2) ? Wih16 + (size_t)(l + 1) * NG * INDIM : (const half_t*)nullptr;

        hipMemsetAsync(h_pub, 0, HPUB_B + 512, stream);

        int grid = (l < 2) ? (2 * BPD + GEMM_BLKS) : (2 * BPD);
        scan_gemm<<<dim3(grid), dim3(256), 0, stream>>>(
            Whh, bih, bhh, gates, bs, h_pub, flags, xout16, out32, l, gA, gW);
    }
}